// Round 12
// baseline (186.226 us; speedup 1.0000x reference)
//
#include <hip/hip_runtime.h>
#include <hip/hip_bf16.h>

#define B_   2
#define T_   2048
#define C_   1024
#define H_   16
#define KV_  4
#define HD_  64
#define M_   (B_*T_)     // 4096 tokens
#define QSTR_ 1024       // qkvb row stride: Q only (k/v redirected to ktb/vfb)
#define PST_ 72          // P LDS row stride (bf16): 144 B
#define M8L2E_ 11.5415603f   // 8 * log2(e)

typedef __bf16 bf16x8 __attribute__((ext_vector_type(8)));
typedef float  f32x4  __attribute__((ext_vector_type(4)));

static __device__ __forceinline__ unsigned short f2bf(float f) {
    __hip_bfloat16 h = __float2bfloat16(f);
    return __builtin_bit_cast(unsigned short, h);
}
static __device__ __forceinline__ unsigned int pk2(float a, float b) {
    return (unsigned int)f2bf(a) | ((unsigned int)f2bf(b) << 16);
}
// NOTE (r6 failure): v_cvt_pk_bf16_f32 inline asm as "lo=src0,hi=src1" produced absmax 1.83
// (vs 0.0078 with pk2) — operand-order/semantics assumption wrong on this toolchain.
// NOTE (r10 failure): fp32-A gemm1 (skip x-cast) cost +6us: cast saves only ~24MB traffic
// but fp32 staging doubles A-LDS + staging issues. Keep prep x-cast + bf16 gemm A.

// ---------------------------------------------------------------- prep: cast x + 4 weight transposes
__global__ void prep_kernel(const float* __restrict__ x, unsigned short* __restrict__ xb,
                            const float* __restrict__ Wq, const float* __restrict__ Wk,
                            const float* __restrict__ Wv, const float* __restrict__ Wo,
                            unsigned short* __restrict__ wtqkv, unsigned short* __restrict__ wto) {
    __shared__ float tile[32][33];
    int bid = blockIdx.x;
    if (bid < 4096) {   // cast x -> bf16
        int i = (bid * 256 + threadIdx.x) * 4;
        float4 v = *(const float4*)(x + i);
        ushort4 o = make_ushort4(f2bf(v.x), f2bf(v.y), f2bf(v.z), f2bf(v.w));
        *(ushort4*)(xb + i) = o;
        return;
    }
    bid -= 4096;
    const float* src; unsigned short* dst; int s, nlog;
    if (bid < 1024)      { src = Wq; dst = wtqkv;               s = bid;        nlog = 5; }
    else if (bid < 1280) { src = Wk; dst = wtqkv + 1024 * 1024; s = bid - 1024; nlog = 3; }
    else if (bid < 1536) { src = Wv; dst = wtqkv + 1280 * 1024; s = bid - 1280; nlog = 3; }
    else                 { src = Wo; dst = wto;                 s = bid - 1536; nlog = 5; }
    int N  = 32 << nlog;
    int k0 = (s >> nlog) * 32, n0 = (s & ((1 << nlog) - 1)) * 32;
    int lr = threadIdx.x >> 5, lc = threadIdx.x & 31;
    #pragma unroll
    for (int i = 0; i < 4; i++) {
        int r = lr + i * 8;
        tile[r][lc] = src[(k0 + r) * N + n0 + lc];
    }
    __syncthreads();
    #pragma unroll
    for (int i = 0; i < 4; i++) {
        int r = lr + i * 8;
        dst[(n0 + r) * 1024 + k0 + lc] = f2bf(tile[lc][r]);
    }
}

// ------------------------------------------------ 128x64 bf16 MFMA GEMM, K=1024/KSPLIT, BK=64
// KSPLIT>1 (gemm2): grid = KSPLIT x NH*32; block ks computes K in [ks*KLEN,(ks+1)*KLEN)
// and ACCUMULATES into fp32 C via unsafeAtomicAdd (hw global_atomic_add_f32, device scope).
// Exactly 2 commutative fp32 adds per element -> bit-deterministic; out zeroed by explicit
// hipMemsetAsync in kernel_launch (no reliance on harness re-poison).
// Rationale: gemm2's grid 512 = 2 blocks/CU (8/32 waves) left the 2-barrier K-loop with no
// cross-block latency hiding; split doubles resident blocks to 4/CU.
// 1D grid with BIJECTIVE XCD-CHUNK SWIZZLE (T1), m-major within XCD (r7: -3.7us total).
// ROPE=true: heads 0..15 q (RoPE+RMS, *0.125*log2e) -> qkvb (stride 1024);
//   16..19 k (RoPE+RMS) -> ktb in MFMA-FRAGMENT ORDER:
//        elem(t,d) at (t>>4)*1024 + (d>>5)*512 + (t&15)*32 + (d&31)
//   20..23 v -> vfb in fragment order: ((t>>5)*4 + (d>>4))*512 + (d&15)*32 + (t&31)
// so attn's K/V fragment loads are single CONTIGUOUS 1KB wave loads (r5: attn 73->49us).
template <typename T, bool ROPE, int NH, int KSPLIT>
__global__ __launch_bounds__(256) void gemm_kernel(const unsigned short* __restrict__ A,
                                                   const unsigned short* __restrict__ Bt,
                                                   T* __restrict__ Cm, int Ni,
                                                   const float* __restrict__ cosb,
                                                   const float* __restrict__ sinb,
                                                   unsigned short* __restrict__ vfb,
                                                   unsigned short* __restrict__ ktb) {
    __shared__ __align__(16) unsigned short As[2][128 * 32];
    __shared__ __align__(16) unsigned short Bs[2][64 * 32];
    int bid = blockIdx.x;
    int ks = 0;
    if constexpr (KSPLIT > 1) { ks = bid / (NH * 32); bid -= ks * (NH * 32); }
    int swz = (bid & 7) * (NH * 4) + (bid >> 3);   // per-half nwg = NH*32, divisible by 8
    int head = swz % NH;
    int m0 = (swz / NH) * 128;
    int n0 = head * 64;
    int tid = threadIdx.x;
    int w = tid >> 6, lane = tid & 63;
    int col = lane & 15, quad = lane >> 4;
    int wm = w * 32;
    int ar = tid >> 2, ak = (tid & 3) * 8;
    constexpr int KLEN = 1024 / KSPLIT;

    f32x4 acc[2][4];
    #pragma unroll
    for (int mt = 0; mt < 2; mt++)
        #pragma unroll
        for (int nt = 0; nt < 4; nt++) acc[mt][nt] = (f32x4){0.f, 0.f, 0.f, 0.f};

    for (int k0 = ks * KLEN; k0 < (ks + 1) * KLEN; k0 += 64) {
        #pragma unroll
        for (int hh = 0; hh < 2; hh++) {
            __builtin_amdgcn_global_load_lds(
                (const __attribute__((address_space(1))) unsigned int*)(A + (size_t)(m0 + ar) * 1024 + k0 + hh * 32 + ak),
                (__attribute__((address_space(3))) unsigned int*)(&As[hh][ar * 32 + ak]), 16, 0, 0);
            __builtin_amdgcn_global_load_lds(
                (const __attribute__((address_space(1))) unsigned int*)(A + (size_t)(m0 + ar + 64) * 1024 + k0 + hh * 32 + ak),
                (__attribute__((address_space(3))) unsigned int*)(&As[hh][(ar + 64) * 32 + ak]), 16, 0, 0);
            __builtin_amdgcn_global_load_lds(
                (const __attribute__((address_space(1))) unsigned int*)(Bt + (size_t)(n0 + ar) * 1024 + k0 + hh * 32 + ak),
                (__attribute__((address_space(3))) unsigned int*)(&Bs[hh][ar * 32 + ak]), 16, 0, 0);
        }
        __syncthreads();
        bf16x8 af[2][2], bfr[4][2];
        #pragma unroll
        for (int hh = 0; hh < 2; hh++) {
            #pragma unroll
            for (int mt = 0; mt < 2; mt++) af[mt][hh]  = *(const bf16x8*)&As[hh][(wm + mt * 16 + col) * 32 + quad * 8];
            #pragma unroll
            for (int nt = 0; nt < 4; nt++) bfr[nt][hh] = *(const bf16x8*)&Bs[hh][(nt * 16 + col) * 32 + quad * 8];
        }
        #pragma unroll
        for (int hh = 0; hh < 2; hh++)
            #pragma unroll
            for (int mt = 0; mt < 2; mt++)
                #pragma unroll
                for (int nt = 0; nt < 4; nt++)
                    acc[mt][nt] = __builtin_amdgcn_mfma_f32_16x16x32_bf16(af[mt][hh], bfr[nt][hh], acc[mt][nt], 0, 0, 0);
        __syncthreads();
    }

    if constexpr (ROPE) {
        int b = m0 >> 11;
        if (head >= H_ + KV_) {
            // v head: fragment-ordered vfb write, uint2 (4 consecutive t at fixed d)
            int kvh = head - (H_ + KV_);
            unsigned short* vbase = vfb + (size_t)(b * KV_ + kvh) * (T_ * 64);
            #pragma unroll
            for (int mt = 0; mt < 2; mt++) {
                int tb = (m0 + wm + mt * 16 + quad * 4) & (T_ - 1);
                #pragma unroll
                for (int nt = 0; nt < 4; nt++) {
                    uint2 pv;
                    pv.x = pk2(acc[mt][nt][0], acc[mt][nt][1]);
                    pv.y = pk2(acc[mt][nt][2], acc[mt][nt][3]);
                    *(uint2*)&vbase[((tb >> 5) * 4 + nt) * 512 + col * 32 + (tb & 31)] = pv;
                }
            }
            return;
        }
        // q/k head: RoPE + RMSNorm
        #pragma unroll
        for (int mt = 0; mt < 2; mt++)
            #pragma unroll
            for (int r = 0; r < 4; r++) {
                int t = (m0 + wm + mt * 16 + quad * 4 + r) & (T_ - 1);
                float nv[4];
                #pragma unroll
                for (int nt = 0; nt < 4; nt++) {
                    int i = (nt & 1) * 16 + col;
                    float c = cosb[t * 32 + i], s = sinb[t * 32 + i];
                    float v = acc[mt][nt][r], p = acc[mt][nt ^ 2][r];
                    nv[nt] = (nt < 2) ? (v * c + p * s) : (v * c - p * s);
                }
                float sq = nv[0] * nv[0] + nv[1] * nv[1] + nv[2] * nv[2] + nv[3] * nv[3];
                sq += __shfl_xor(sq, 1, 64);
                sq += __shfl_xor(sq, 2, 64);
                sq += __shfl_xor(sq, 4, 64);
                sq += __shfl_xor(sq, 8, 64);
                float rr = rsqrtf(sq * (1.0f / 64.0f) + 1e-6f);
                if (head < H_) rr *= 0.125f * 1.44269504f;   // attn scale * log2(e) folded into q
                #pragma unroll
                for (int nt = 0; nt < 4; nt++) acc[mt][nt][r] = nv[nt] * rr;
            }
        if (head >= H_) {
            // k head: fragment-ordered ktb write (elementwise, same count as old C-write)
            int kvh = head - H_;
            unsigned short* kbase = ktb + (size_t)(b * KV_ + kvh) * (T_ * 64);
            #pragma unroll
            for (int mt = 0; mt < 2; mt++)
                #pragma unroll
                for (int r = 0; r < 4; r++) {
                    int t = (m0 + wm + mt * 16 + quad * 4 + r) & (T_ - 1);
                    #pragma unroll
                    for (int nt = 0; nt < 4; nt++) {
                        int dd = nt * 16 + col;
                        kbase[(t >> 4) * 1024 + (dd >> 5) * 512 + (t & 15) * 32 + (dd & 31)] = f2bf(acc[mt][nt][r]);
                    }
                }
            return;
        }
    }

    #pragma unroll
    for (int mt = 0; mt < 2; mt++)
        #pragma unroll
        for (int nt = 0; nt < 4; nt++)
            #pragma unroll
            for (int r = 0; r < 4; r++) {
                size_t idx = (size_t)(m0 + wm + mt * 16 + quad * 4 + r) * Ni + n0 + nt * 16 + col;
                if constexpr (KSPLIT > 1)      unsafeAtomicAdd((float*)&Cm[idx], acc[mt][nt][r]);
                else if constexpr (sizeof(T) == 2) Cm[idx] = f2bf(acc[mt][nt][r]);
                else                          Cm[idx] = acc[mt][nt][r];
            }
}

// ------------------------------------------------ MFMA flash attention: split-K, S^T trick
// r11 proven version (47.5us): r7 structure + T5 s_setprio(1) around MFMA clusters (-3%).
// Fragment-ordered ktb/vfb: every K/V fragment load is one contiguous 1KB wave load
// (4 coalesced transactions, not a 16-line gather) — r5: attn 73->49us.
// BALANCED PAIRING: nkt(qt)+nkt(63-qt)==33 -> block handles pair (63-pi, pi): 1024
// identical blocks, all co-resident, zero tail, zero imbalance.
// NOTE: plain __launch_bounds__(256). min-waves=4 once forced VGPR to 64 -> 95 MB spill. Never re-add.
// QK^T computed TRANSPOSED (A=K, B=Q); P->LDS b64; PV reads P q-major b128 (all-register
// PV regressed r3; K-prefetch null r8). Fixed-max softmax via exp2 (log2e folded into q).
__global__ __launch_bounds__(256) void attn_kernel(const unsigned short* __restrict__ qkvb,
                                                   const unsigned short* __restrict__ ktb,
                                                   const unsigned short* __restrict__ vfb,
                                                   unsigned short* __restrict__ yb) {
    __shared__ __align__(16) char smem[4 * 32 * 64 * 4];   // 32 KB: P stripes (loop) / Obuf fp32 (merge)
    __shared__ float lbuf[4][32];

    int bh = blockIdx.x & 31;
    int pi = blockIdx.x >> 5;               // pair index 0..31
    int b = bh >> 4, h = bh & 15, kvh = h >> 2;
    int tid = threadIdx.x;
    int w = tid >> 6, lane = tid & 63;
    int col = lane & 15, quad = lane >> 4;

    unsigned short* Ps = (unsigned short*)smem + w * (32 * PST_);
    float* Obuf = (float*)smem;

    const unsigned short* kfb = ktb + (size_t)(b * KV_ + kvh) * (T_ * 64);
    const unsigned short* vfp = vfb + (size_t)(b * KV_ + kvh) * (T_ * 64);

    bf16x8 ones;
    #pragma unroll
    for (int j = 0; j < 8; j++) ones[j] = (__bf16)1.0f;

    for (int ti = 0; ti < 2; ti++) {
        int qt = ti ? pi : 63 - pi;         // big tile first
        int t0 = qt * 32;
        int nkt = (t0 + 95) >> 6;           // 64-key tiles covering keys <= t0+31
        int we = ti ? 3 - w : w;            // reversed wave order on 2nd tile

        // Q B-frags (loop-invariant per tile): lane(col=q, quad) holds Q[t0+ntq*16+col][quad*8+step*32..]
        bf16x8 aq[2][2];
        #pragma unroll
        for (int ntq = 0; ntq < 2; ntq++)
            #pragma unroll
            for (int step = 0; step < 2; step++)
                aq[ntq][step] = *(const bf16x8*)&qkvb[(size_t)(b * T_ + t0 + ntq * 16 + col) * QSTR_
                                                      + h * 64 + quad * 8 + step * 32];

        f32x4 o[2][4], lacc[2];
        #pragma unroll
        for (int mt = 0; mt < 2; mt++) {
            lacc[mt] = (f32x4){0.f, 0.f, 0.f, 0.f};
            #pragma unroll
            for (int nt = 0; nt < 4; nt++) o[mt][nt] = (f32x4){0.f, 0.f, 0.f, 0.f};
        }

        for (int kt = we; kt < nkt; kt += 4) {
            // S^T = K Q^T : A-frag = K rows (key), B-frag = Q
            // kb load: one contiguous 1KB wave load from fragment-ordered ktb
            f32x4 sacc[4][2];
            #pragma unroll
            for (int mtk = 0; mtk < 4; mtk++)
                #pragma unroll
                for (int ntq = 0; ntq < 2; ntq++) sacc[mtk][ntq] = (f32x4){0.f, 0.f, 0.f, 0.f};
            #pragma unroll
            for (int step = 0; step < 2; step++) {
                bf16x8 kb[4];
                #pragma unroll
                for (int mtk = 0; mtk < 4; mtk++)
                    kb[mtk] = *(const bf16x8*)&kfb[(kt * 4 + mtk) * 1024 + step * 512 + col * 32 + quad * 8];
                __builtin_amdgcn_s_setprio(1);
                #pragma unroll
                for (int mtk = 0; mtk < 4; mtk++)
                    #pragma unroll
                    for (int ntq = 0; ntq < 2; ntq++)
                        sacc[mtk][ntq] = __builtin_amdgcn_mfma_f32_16x16x32_bf16(kb[mtk], aq[ntq][step], sacc[mtk][ntq], 0, 0, 0);
                __builtin_amdgcn_s_setprio(0);
            }
            // issue V loads (contiguous 1KB each); latency hides under exp/pack
            bf16x8 vb[2][4];
            #pragma unroll
            for (int step = 0; step < 2; step++)
                #pragma unroll
                for (int ntd = 0; ntd < 4; ntd++)
                    vb[step][ntd] = *(const bf16x8*)&vfp[((kt * 2 + step) * 4 + ntd) * 512 + col * 32 + quad * 8];
            if (kt == nkt - 1) {   // diagonal: causal mask (S^T indices: row=key, col=q)
                #pragma unroll
                for (int mtk = 0; mtk < 4; mtk++)
                    #pragma unroll
                    for (int ntq = 0; ntq < 2; ntq++)
                        #pragma unroll
                        for (int r = 0; r < 4; r++)
                            if (kt * 64 + mtk * 16 + quad * 4 + r > t0 + ntq * 16 + col)
                                sacc[mtk][ntq][r] = -1e30f;
            }
            // p = 2^(s' - 8*log2e); lane's 4 values are key-consecutive -> one b64 write each
            #pragma unroll
            for (int mtk = 0; mtk < 4; mtk++)
                #pragma unroll
                for (int ntq = 0; ntq < 2; ntq++) {
                    uint2 pw;
                    pw.x = pk2(__builtin_amdgcn_exp2f(sacc[mtk][ntq][0] - M8L2E_),
                               __builtin_amdgcn_exp2f(sacc[mtk][ntq][1] - M8L2E_));
                    pw.y = pk2(__builtin_amdgcn_exp2f(sacc[mtk][ntq][2] - M8L2E_),
                               __builtin_amdgcn_exp2f(sacc[mtk][ntq][3] - M8L2E_));
                    *(uint2*)&Ps[(ntq * 16 + col) * PST_ + mtk * 16 + quad * 4] = pw;
                }
            // O += P V ; l += P * ones  (P read q-major as A-frag, b128)
            #pragma unroll
            for (int step = 0; step < 2; step++) {
                bf16x8 ap[2];
                #pragma unroll
                for (int mtq = 0; mtq < 2; mtq++)
                    ap[mtq] = *(const bf16x8*)&Ps[(mtq * 16 + col) * PST_ + quad * 8 + step * 32];
                __builtin_amdgcn_s_setprio(1);
                #pragma unroll
                for (int ntd = 0; ntd < 4; ntd++)
                    #pragma unroll
                    for (int mtq = 0; mtq < 2; mtq++)
                        o[mtq][ntd] = __builtin_amdgcn_mfma_f32_16x16x32_bf16(ap[mtq], vb[step][ntd], o[mtq][ntd], 0, 0, 0);
                #pragma unroll
                for (int mtq = 0; mtq < 2; mtq++)
                    lacc[mtq] = __builtin_amdgcn_mfma_f32_16x16x32_bf16(ap[mtq], ones, lacc[mtq], 0, 0, 0);
                __builtin_amdgcn_s_setprio(0);
            }
        }

        __syncthreads();   // all waves done with P space
        #pragma unroll
        for (int mt = 0; mt < 2; mt++)
            #pragma unroll
            for (int nt = 0; nt < 4; nt++)
                #pragma unroll
                for (int r = 0; r < 4; r++)
                    Obuf[w * 2048 + (mt * 16 + quad * 4 + r) * 64 + nt * 16 + col] = o[mt][nt][r];
        if (col == 0) {
            #pragma unroll
            for (int mt = 0; mt < 2; mt++)
                #pragma unroll
                for (int r = 0; r < 4; r++)
                    lbuf[w][mt * 16 + quad * 4 + r] = lacc[mt][r];
        }
        __syncthreads();
        {
            int row = tid >> 3, d0 = (tid & 7) * 8;
            float ls = lbuf[0][row] + lbuf[1][row] + lbuf[2][row] + lbuf[3][row];
            float inv = 1.0f / ls;
            float s[8];
            #pragma unroll
            for (int j = 0; j < 8; j++) s[j] = 0.f;
            #pragma unroll
            for (int wv = 0; wv < 4; wv++) {
                f32x4 p0 = *(const f32x4*)&Obuf[wv * 2048 + row * 64 + d0];
                f32x4 p1 = *(const f32x4*)&Obuf[wv * 2048 + row * 64 + d0 + 4];
                #pragma unroll
                for (int j = 0; j < 4; j++) { s[j] += p0[j]; s[4 + j] += p1[j]; }
            }
            unsigned short o8[8];
            #pragma unroll
            for (int j = 0; j < 8; j++) o8[j] = f2bf(s[j] * inv);
            *(uint4*)&yb[(size_t)(b * T_ + t0 + row) * C_ + h * 64 + d0] = *(uint4*)o8;
        }
        __syncthreads();   // merge reads done before next tile reuses Obuf
    }
}

// ---------------------------------------------------------------- launch
extern "C" void kernel_launch(void* const* d_in, const int* in_sizes, int n_in,
                              void* d_out, int out_size, void* d_ws, size_t ws_size,
                              hipStream_t stream) {
    const float* x    = (const float*)d_in[0];
    const float* cosb = (const float*)d_in[1];
    const float* sinb = (const float*)d_in[2];
    const float* Wq   = (const float*)d_in[3];
    const float* Wk   = (const float*)d_in[4];
    const float* Wv   = (const float*)d_in[5];
    const float* Wo   = (const float*)d_in[6];
    float* out = (float*)d_out;

    char* ws = (char*)d_ws;
    unsigned short* xb    = (unsigned short*)(ws);               // 8 MB (reused as yb)
    unsigned short* yb    = (unsigned short*)(ws);               // alias: xb dead after QKV GEMM
    unsigned short* wtqkv = (unsigned short*)(ws + ( 8u << 20)); // 3 MB
    unsigned short* wto   = (unsigned short*)(ws + (11u << 20)); // 2 MB
    unsigned short* qkvb  = (unsigned short*)(ws + (13u << 20)); // 8 MB (Q only, stride 1024)
    unsigned short* vfb   = (unsigned short*)(ws + (21u << 20)); // 2 MB fragment-ordered V
    unsigned short* ktb   = (unsigned short*)(ws + (23u << 20)); // 2 MB fragment-ordered K

    // zero out for gemm2's K-split atomic accumulation (graph-capturable async memset)
    hipMemsetAsync(out, 0, (size_t)M_ * C_ * sizeof(float), stream);
    prep_kernel<<<4096 + 2560, 256, 0, stream>>>(x, xb, Wq, Wk, Wv, Wo, wtqkv, wto);
    // QKV projection + fused RoPE/RMSNorm; q -> qkvb, k -> ktb (frag order), v -> vfb (frag order)
    // 1D grid 768 = 24 heads x 32 m-blocks, XCD-chunk swizzled (m-major per XCD)
    gemm_kernel<unsigned short, true, 24, 1><<<768, 256, 0, stream>>>(xb, wtqkv, qkvb, QSTR_, cosb, sinb, vfb, ktb);
    // split-K flash attention, balanced qt-pairing, coalesced fragment loads, setprio MFMA
    attn_kernel<<<1024, 256, 0, stream>>>(qkvb, ktb, vfb, yb);
    // output projection -> fp32 out; K-split=2: 1024 blocks (4/CU), atomic fp32 accumulate
    gemm_kernel<float, false, 16, 2><<<1024, 256, 0, stream>>>(yb, wto, out, C_, nullptr, nullptr, nullptr, nullptr);
}

// Round 13
// 162.823 us; speedup vs baseline: 1.1437x; 1.1437x over previous
//
#include <hip/hip_runtime.h>
#include <hip/hip_bf16.h>

#define B_   2
#define T_   2048
#define C_   1024
#define H_   16
#define KV_  4
#define HD_  64
#define M_   (B_*T_)     // 4096 tokens
#define QSTR_ 1024       // qkvb row stride: Q only (k/v redirected to ktb/vfb)
#define PST_ 72          // P LDS row stride (bf16): 144 B
#define M8L2E_ 11.5415603f   // 8 * log2(e)

typedef __bf16 bf16x8 __attribute__((ext_vector_type(8)));
typedef float  f32x4  __attribute__((ext_vector_type(4)));

static __device__ __forceinline__ unsigned short f2bf(float f) {
    __hip_bfloat16 h = __float2bfloat16(f);
    return __builtin_bit_cast(unsigned short, h);
}
static __device__ __forceinline__ unsigned int pk2(float a, float b) {
    return (unsigned int)f2bf(a) | ((unsigned int)f2bf(b) << 16);
}
// truncation pack (RTZ for positive values): 3 bit-ops vs ~12 for RNE pk2. Valid ONLY for
// P (softmax weights): P>=0 and O = sum(P*V)/sum(P) renormalizes -> uniform pack error
// cancels to first order. Do NOT use for V or y (their error lands directly in output).
static __device__ __forceinline__ unsigned int pk2t(float a, float b) {
    return (__builtin_bit_cast(unsigned int, a) >> 16)
         | (__builtin_bit_cast(unsigned int, b) & 0xFFFF0000u);
}
// NOTE (r6 failure): v_cvt_pk_bf16_f32 inline asm produced absmax 1.83 — operand-order/
// semantics assumption wrong on this toolchain. Never reintroduce without isolated refcheck.
// NOTE (r10 failure): fp32-A gemm1 (skip x-cast) cost +6us. Keep prep x-cast + bf16 gemm A.
// NOTE (r12 failure): K-split gemm2 via per-lane fp32 atomics cost +22us (uncoalesced
// 4B atomics + memset + 2x write traffic). Keep plain 512-block gemm2.

// ---------------------------------------------------------------- prep: cast x + 4 weight transposes
__global__ void prep_kernel(const float* __restrict__ x, unsigned short* __restrict__ xb,
                            const float* __restrict__ Wq, const float* __restrict__ Wk,
                            const float* __restrict__ Wv, const float* __restrict__ Wo,
                            unsigned short* __restrict__ wtqkv, unsigned short* __restrict__ wto) {
    __shared__ float tile[32][33];
    int bid = blockIdx.x;
    if (bid < 4096) {   // cast x -> bf16
        int i = (bid * 256 + threadIdx.x) * 4;
        float4 v = *(const float4*)(x + i);
        ushort4 o = make_ushort4(f2bf(v.x), f2bf(v.y), f2bf(v.z), f2bf(v.w));
        *(ushort4*)(xb + i) = o;
        return;
    }
    bid -= 4096;
    const float* src; unsigned short* dst; int s, nlog;
    if (bid < 1024)      { src = Wq; dst = wtqkv;               s = bid;        nlog = 5; }
    else if (bid < 1280) { src = Wk; dst = wtqkv + 1024 * 1024; s = bid - 1024; nlog = 3; }
    else if (bid < 1536) { src = Wv; dst = wtqkv + 1280 * 1024; s = bid - 1280; nlog = 3; }
    else                 { src = Wo; dst = wto;                 s = bid - 1536; nlog = 5; }
    int N  = 32 << nlog;
    int k0 = (s >> nlog) * 32, n0 = (s & ((1 << nlog) - 1)) * 32;
    int lr = threadIdx.x >> 5, lc = threadIdx.x & 31;
    #pragma unroll
    for (int i = 0; i < 4; i++) {
        int r = lr + i * 8;
        tile[r][lc] = src[(k0 + r) * N + n0 + lc];
    }
    __syncthreads();
    #pragma unroll
    for (int i = 0; i < 4; i++) {
        int r = lr + i * 8;
        dst[(n0 + r) * 1024 + k0 + lc] = f2bf(tile[lc][r]);
    }
}

// ------------------------------------------------ 128x64 bf16 MFMA GEMM, K=1024, BK=64
// 1D grid with BIJECTIVE XCD-CHUNK SWIZZLE (T1), m-major within XCD: XCD x gets swz in
// [x*NH*4, (x+1)*NH*4) = 4 m-blocks x all NH heads. Per-XCD working set = A(1MB)+B(3MB)
// = L2-sized; each 256KB A panel fetched by exactly ONE XCD. (r7: -3.7us total.)
// ROPE=true: heads 0..15 q (RoPE+RMS, *0.125*log2e) -> qkvb (stride 1024);
//   16..19 k (RoPE+RMS) -> ktb in MFMA-FRAGMENT ORDER:
//        elem(t,d) at (t>>4)*1024 + (d>>5)*512 + (t&15)*32 + (d&31)
//   20..23 v -> vfb in fragment order: ((t>>5)*4 + (d>>4))*512 + (d&15)*32 + (t&31)
// so attn's K/V fragment loads are single CONTIGUOUS 1KB wave loads (r5: attn 73->49us).
template <typename T, bool ROPE, int NH>
__global__ __launch_bounds__(256) void gemm_kernel(const unsigned short* __restrict__ A,
                                                   const unsigned short* __restrict__ Bt,
                                                   T* __restrict__ Cm, int Ni,
                                                   const float* __restrict__ cosb,
                                                   const float* __restrict__ sinb,
                                                   unsigned short* __restrict__ vfb,
                                                   unsigned short* __restrict__ ktb) {
    __shared__ __align__(16) unsigned short As[2][128 * 32];
    __shared__ __align__(16) unsigned short Bs[2][64 * 32];
    int bid = blockIdx.x;
    int swz = (bid & 7) * (NH * 4) + (bid >> 3);   // nwg = NH*32, divisible by 8
    int head = swz % NH;
    int m0 = (swz / NH) * 128;
    int n0 = head * 64;
    int tid = threadIdx.x;
    int w = tid >> 6, lane = tid & 63;
    int col = lane & 15, quad = lane >> 4;
    int wm = w * 32;
    int ar = tid >> 2, ak = (tid & 3) * 8;

    f32x4 acc[2][4];
    #pragma unroll
    for (int mt = 0; mt < 2; mt++)
        #pragma unroll
        for (int nt = 0; nt < 4; nt++) acc[mt][nt] = (f32x4){0.f, 0.f, 0.f, 0.f};

    for (int k0 = 0; k0 < 1024; k0 += 64) {
        #pragma unroll
        for (int hh = 0; hh < 2; hh++) {
            __builtin_amdgcn_global_load_lds(
                (const __attribute__((address_space(1))) unsigned int*)(A + (size_t)(m0 + ar) * 1024 + k0 + hh * 32 + ak),
                (__attribute__((address_space(3))) unsigned int*)(&As[hh][ar * 32 + ak]), 16, 0, 0);
            __builtin_amdgcn_global_load_lds(
                (const __attribute__((address_space(1))) unsigned int*)(A + (size_t)(m0 + ar + 64) * 1024 + k0 + hh * 32 + ak),
                (__attribute__((address_space(3))) unsigned int*)(&As[hh][(ar + 64) * 32 + ak]), 16, 0, 0);
            __builtin_amdgcn_global_load_lds(
                (const __attribute__((address_space(1))) unsigned int*)(Bt + (size_t)(n0 + ar) * 1024 + k0 + hh * 32 + ak),
                (__attribute__((address_space(3))) unsigned int*)(&Bs[hh][ar * 32 + ak]), 16, 0, 0);
        }
        __syncthreads();
        bf16x8 af[2][2], bfr[4][2];
        #pragma unroll
        for (int hh = 0; hh < 2; hh++) {
            #pragma unroll
            for (int mt = 0; mt < 2; mt++) af[mt][hh]  = *(const bf16x8*)&As[hh][(wm + mt * 16 + col) * 32 + quad * 8];
            #pragma unroll
            for (int nt = 0; nt < 4; nt++) bfr[nt][hh] = *(const bf16x8*)&Bs[hh][(nt * 16 + col) * 32 + quad * 8];
        }
        #pragma unroll
        for (int hh = 0; hh < 2; hh++)
            #pragma unroll
            for (int mt = 0; mt < 2; mt++)
                #pragma unroll
                for (int nt = 0; nt < 4; nt++)
                    acc[mt][nt] = __builtin_amdgcn_mfma_f32_16x16x32_bf16(af[mt][hh], bfr[nt][hh], acc[mt][nt], 0, 0, 0);
        __syncthreads();
    }

    if constexpr (ROPE) {
        int b = m0 >> 11;
        if (head >= H_ + KV_) {
            // v head: fragment-ordered vfb write, uint2 (4 consecutive t at fixed d); RNE pack
            int kvh = head - (H_ + KV_);
            unsigned short* vbase = vfb + (size_t)(b * KV_ + kvh) * (T_ * 64);
            #pragma unroll
            for (int mt = 0; mt < 2; mt++) {
                int tb = (m0 + wm + mt * 16 + quad * 4) & (T_ - 1);
                #pragma unroll
                for (int nt = 0; nt < 4; nt++) {
                    uint2 pv;
                    pv.x = pk2(acc[mt][nt][0], acc[mt][nt][1]);
                    pv.y = pk2(acc[mt][nt][2], acc[mt][nt][3]);
                    *(uint2*)&vbase[((tb >> 5) * 4 + nt) * 512 + col * 32 + (tb & 31)] = pv;
                }
            }
            return;
        }
        // q/k head: RoPE + RMSNorm
        #pragma unroll
        for (int mt = 0; mt < 2; mt++)
            #pragma unroll
            for (int r = 0; r < 4; r++) {
                int t = (m0 + wm + mt * 16 + quad * 4 + r) & (T_ - 1);
                float nv[4];
                #pragma unroll
                for (int nt = 0; nt < 4; nt++) {
                    int i = (nt & 1) * 16 + col;
                    float c = cosb[t * 32 + i], s = sinb[t * 32 + i];
                    float v = acc[mt][nt][r], p = acc[mt][nt ^ 2][r];
                    nv[nt] = (nt < 2) ? (v * c + p * s) : (v * c - p * s);
                }
                float sq = nv[0] * nv[0] + nv[1] * nv[1] + nv[2] * nv[2] + nv[3] * nv[3];
                sq += __shfl_xor(sq, 1, 64);
                sq += __shfl_xor(sq, 2, 64);
                sq += __shfl_xor(sq, 4, 64);
                sq += __shfl_xor(sq, 8, 64);
                float rr = rsqrtf(sq * (1.0f / 64.0f) + 1e-6f);
                if (head < H_) rr *= 0.125f * 1.44269504f;   // attn scale * log2(e) folded into q
                #pragma unroll
                for (int nt = 0; nt < 4; nt++) acc[mt][nt][r] = nv[nt] * rr;
            }
        if (head >= H_) {
            // k head: fragment-ordered ktb write (elementwise, same count as old C-write)
            int kvh = head - H_;
            unsigned short* kbase = ktb + (size_t)(b * KV_ + kvh) * (T_ * 64);
            #pragma unroll
            for (int mt = 0; mt < 2; mt++)
                #pragma unroll
                for (int r = 0; r < 4; r++) {
                    int t = (m0 + wm + mt * 16 + quad * 4 + r) & (T_ - 1);
                    #pragma unroll
                    for (int nt = 0; nt < 4; nt++) {
                        int dd = nt * 16 + col;
                        kbase[(t >> 4) * 1024 + (dd >> 5) * 512 + (t & 15) * 32 + (dd & 31)] = f2bf(acc[mt][nt][r]);
                    }
                }
            return;
        }
    }

    #pragma unroll
    for (int mt = 0; mt < 2; mt++)
        #pragma unroll
        for (int nt = 0; nt < 4; nt++)
            #pragma unroll
            for (int r = 0; r < 4; r++) {
                size_t idx = (size_t)(m0 + wm + mt * 16 + quad * 4 + r) * Ni + n0 + nt * 16 + col;
                if constexpr (sizeof(T) == 2) Cm[idx] = f2bf(acc[mt][nt][r]);
                else                          Cm[idx] = acc[mt][nt][r];
            }
}

// ------------------------------------------------ MFMA flash attention: split-K, S^T trick
// r11 proven version (47.5us): r7 structure + T5 s_setprio(1) around MFMA clusters (-3%).
// r13: P pack via truncation pk2t (hot loop only) — ~100 fewer VALU instrs/iter; error
// cancels in softmax renormalization (O = sum(P*V)/sum(P), l from same packed P).
// Fragment-ordered ktb/vfb: every K/V fragment load is one contiguous 1KB wave load
// (4 coalesced transactions, not a 16-line gather) — r5: attn 73->49us.
// BALANCED PAIRING: nkt(qt)+nkt(63-qt)==33 -> block handles pair (63-pi, pi): 1024
// identical blocks, all co-resident, zero tail, zero imbalance.
// NOTE: plain __launch_bounds__(256). min-waves=4 once forced VGPR to 64 -> 95 MB spill. Never re-add.
// QK^T computed TRANSPOSED (A=K, B=Q); P->LDS b64; PV reads P q-major b128 (all-register
// PV regressed r3; K-prefetch null r8). Fixed-max softmax via exp2 (log2e folded into q).
__global__ __launch_bounds__(256) void attn_kernel(const unsigned short* __restrict__ qkvb,
                                                   const unsigned short* __restrict__ ktb,
                                                   const unsigned short* __restrict__ vfb,
                                                   unsigned short* __restrict__ yb) {
    __shared__ __align__(16) char smem[4 * 32 * 64 * 4];   // 32 KB: P stripes (loop) / Obuf fp32 (merge)
    __shared__ float lbuf[4][32];

    int bh = blockIdx.x & 31;
    int pi = blockIdx.x >> 5;               // pair index 0..31
    int b = bh >> 4, h = bh & 15, kvh = h >> 2;
    int tid = threadIdx.x;
    int w = tid >> 6, lane = tid & 63;
    int col = lane & 15, quad = lane >> 4;

    unsigned short* Ps = (unsigned short*)smem + w * (32 * PST_);
    float* Obuf = (float*)smem;

    const unsigned short* kfb = ktb + (size_t)(b * KV_ + kvh) * (T_ * 64);
    const unsigned short* vfp = vfb + (size_t)(b * KV_ + kvh) * (T_ * 64);

    bf16x8 ones;
    #pragma unroll
    for (int j = 0; j < 8; j++) ones[j] = (__bf16)1.0f;

    for (int ti = 0; ti < 2; ti++) {
        int qt = ti ? pi : 63 - pi;         // big tile first
        int t0 = qt * 32;
        int nkt = (t0 + 95) >> 6;           // 64-key tiles covering keys <= t0+31
        int we = ti ? 3 - w : w;            // reversed wave order on 2nd tile

        // Q B-frags (loop-invariant per tile): lane(col=q, quad) holds Q[t0+ntq*16+col][quad*8+step*32..]
        bf16x8 aq[2][2];
        #pragma unroll
        for (int ntq = 0; ntq < 2; ntq++)
            #pragma unroll
            for (int step = 0; step < 2; step++)
                aq[ntq][step] = *(const bf16x8*)&qkvb[(size_t)(b * T_ + t0 + ntq * 16 + col) * QSTR_
                                                      + h * 64 + quad * 8 + step * 32];

        f32x4 o[2][4], lacc[2];
        #pragma unroll
        for (int mt = 0; mt < 2; mt++) {
            lacc[mt] = (f32x4){0.f, 0.f, 0.f, 0.f};
            #pragma unroll
            for (int nt = 0; nt < 4; nt++) o[mt][nt] = (f32x4){0.f, 0.f, 0.f, 0.f};
        }

        for (int kt = we; kt < nkt; kt += 4) {
            // S^T = K Q^T : A-frag = K rows (key), B-frag = Q
            // kb load: one contiguous 1KB wave load from fragment-ordered ktb
            f32x4 sacc[4][2];
            #pragma unroll
            for (int mtk = 0; mtk < 4; mtk++)
                #pragma unroll
                for (int ntq = 0; ntq < 2; ntq++) sacc[mtk][ntq] = (f32x4){0.f, 0.f, 0.f, 0.f};
            #pragma unroll
            for (int step = 0; step < 2; step++) {
                bf16x8 kb[4];
                #pragma unroll
                for (int mtk = 0; mtk < 4; mtk++)
                    kb[mtk] = *(const bf16x8*)&kfb[(kt * 4 + mtk) * 1024 + step * 512 + col * 32 + quad * 8];
                __builtin_amdgcn_s_setprio(1);
                #pragma unroll
                for (int mtk = 0; mtk < 4; mtk++)
                    #pragma unroll
                    for (int ntq = 0; ntq < 2; ntq++)
                        sacc[mtk][ntq] = __builtin_amdgcn_mfma_f32_16x16x32_bf16(kb[mtk], aq[ntq][step], sacc[mtk][ntq], 0, 0, 0);
                __builtin_amdgcn_s_setprio(0);
            }
            // issue V loads (contiguous 1KB each); latency hides under exp/pack
            bf16x8 vb[2][4];
            #pragma unroll
            for (int step = 0; step < 2; step++)
                #pragma unroll
                for (int ntd = 0; ntd < 4; ntd++)
                    vb[step][ntd] = *(const bf16x8*)&vfp[((kt * 2 + step) * 4 + ntd) * 512 + col * 32 + quad * 8];
            if (kt == nkt - 1) {   // diagonal: causal mask (S^T indices: row=key, col=q)
                #pragma unroll
                for (int mtk = 0; mtk < 4; mtk++)
                    #pragma unroll
                    for (int ntq = 0; ntq < 2; ntq++)
                        #pragma unroll
                        for (int r = 0; r < 4; r++)
                            if (kt * 64 + mtk * 16 + quad * 4 + r > t0 + ntq * 16 + col)
                                sacc[mtk][ntq][r] = -1e30f;
            }
            // p = 2^(s' - 8*log2e); truncation pack (pk2t) — error cancels in renorm
            #pragma unroll
            for (int mtk = 0; mtk < 4; mtk++)
                #pragma unroll
                for (int ntq = 0; ntq < 2; ntq++) {
                    uint2 pw;
                    pw.x = pk2t(__builtin_amdgcn_exp2f(sacc[mtk][ntq][0] - M8L2E_),
                                __builtin_amdgcn_exp2f(sacc[mtk][ntq][1] - M8L2E_));
                    pw.y = pk2t(__builtin_amdgcn_exp2f(sacc[mtk][ntq][2] - M8L2E_),
                                __builtin_amdgcn_exp2f(sacc[mtk][ntq][3] - M8L2E_));
                    *(uint2*)&Ps[(ntq * 16 + col) * PST_ + mtk * 16 + quad * 4] = pw;
                }
            // O += P V ; l += P * ones  (P read q-major as A-frag, b128)
            #pragma unroll
            for (int step = 0; step < 2; step++) {
                bf16x8 ap[2];
                #pragma unroll
                for (int mtq = 0; mtq < 2; mtq++)
                    ap[mtq] = *(const bf16x8*)&Ps[(mtq * 16 + col) * PST_ + quad * 8 + step * 32];
                __builtin_amdgcn_s_setprio(1);
                #pragma unroll
                for (int ntd = 0; ntd < 4; ntd++)
                    #pragma unroll
                    for (int mtq = 0; mtq < 2; mtq++)
                        o[mtq][ntd] = __builtin_amdgcn_mfma_f32_16x16x32_bf16(ap[mtq], vb[step][ntd], o[mtq][ntd], 0, 0, 0);
                #pragma unroll
                for (int mtq = 0; mtq < 2; mtq++)
                    lacc[mtq] = __builtin_amdgcn_mfma_f32_16x16x32_bf16(ap[mtq], ones, lacc[mtq], 0, 0, 0);
                __builtin_amdgcn_s_setprio(0);
            }
        }

        __syncthreads();   // all waves done with P space
        #pragma unroll
        for (int mt = 0; mt < 2; mt++)
            #pragma unroll
            for (int nt = 0; nt < 4; nt++)
                #pragma unroll
                for (int r = 0; r < 4; r++)
                    Obuf[w * 2048 + (mt * 16 + quad * 4 + r) * 64 + nt * 16 + col] = o[mt][nt][r];
        if (col == 0) {
            #pragma unroll
            for (int mt = 0; mt < 2; mt++)
                #pragma unroll
                for (int r = 0; r < 4; r++)
                    lbuf[w][mt * 16 + quad * 4 + r] = lacc[mt][r];
        }
        __syncthreads();
        {
            int row = tid >> 3, d0 = (tid & 7) * 8;
            float ls = lbuf[0][row] + lbuf[1][row] + lbuf[2][row] + lbuf[3][row];
            float inv = 1.0f / ls;
            float s[8];
            #pragma unroll
            for (int j = 0; j < 8; j++) s[j] = 0.f;
            #pragma unroll
            for (int wv = 0; wv < 4; wv++) {
                f32x4 p0 = *(const f32x4*)&Obuf[wv * 2048 + row * 64 + d0];
                f32x4 p1 = *(const f32x4*)&Obuf[wv * 2048 + row * 64 + d0 + 4];
                #pragma unroll
                for (int j = 0; j < 4; j++) { s[j] += p0[j]; s[4 + j] += p1[j]; }
            }
            unsigned short o8[8];
            #pragma unroll
            for (int j = 0; j < 8; j++) o8[j] = f2bf(s[j] * inv);
            *(uint4*)&yb[(size_t)(b * T_ + t0 + row) * C_ + h * 64 + d0] = *(uint4*)o8;
        }
        __syncthreads();   // merge reads done before next tile reuses Obuf
    }
}

// ---------------------------------------------------------------- launch
extern "C" void kernel_launch(void* const* d_in, const int* in_sizes, int n_in,
                              void* d_out, int out_size, void* d_ws, size_t ws_size,
                              hipStream_t stream) {
    const float* x    = (const float*)d_in[0];
    const float* cosb = (const float*)d_in[1];
    const float* sinb = (const float*)d_in[2];
    const float* Wq   = (const float*)d_in[3];
    const float* Wk   = (const float*)d_in[4];
    const float* Wv   = (const float*)d_in[5];
    const float* Wo   = (const float*)d_in[6];
    float* out = (float*)d_out;

    char* ws = (char*)d_ws;
    unsigned short* xb    = (unsigned short*)(ws);               // 8 MB (reused as yb)
    unsigned short* yb    = (unsigned short*)(ws);               // alias: xb dead after QKV GEMM
    unsigned short* wtqkv = (unsigned short*)(ws + ( 8u << 20)); // 3 MB
    unsigned short* wto   = (unsigned short*)(ws + (11u << 20)); // 2 MB
    unsigned short* qkvb  = (unsigned short*)(ws + (13u << 20)); // 8 MB (Q only, stride 1024)
    unsigned short* vfb   = (unsigned short*)(ws + (21u << 20)); // 2 MB fragment-ordered V
    unsigned short* ktb   = (unsigned short*)(ws + (23u << 20)); // 2 MB fragment-ordered K

    prep_kernel<<<4096 + 2560, 256, 0, stream>>>(x, xb, Wq, Wk, Wv, Wo, wtqkv, wto);
    // QKV projection + fused RoPE/RMSNorm; q -> qkvb, k -> ktb (frag order), v -> vfb (frag order)
    // 1D grid 768 = 24 heads x 32 m-blocks, XCD-chunk swizzled (m-major per XCD)
    gemm_kernel<unsigned short, true, 24><<<768, 256, 0, stream>>>(xb, wtqkv, qkvb, QSTR_, cosb, sinb, vfb, ktb);
    // split-K flash attention, balanced qt-pairing, coalesced fragment loads, setprio MFMA
    attn_kernel<<<1024, 256, 0, stream>>>(qkvb, ktb, vfb, yb);
    // output projection -> fp32 out; 1D grid 512 = 16 x 32, XCD-chunk swizzled
    gemm_kernel<float, false, 16><<<512, 256, 0, stream>>>(yb, wto, out, C_, nullptr, nullptr, nullptr, nullptr);
}

// Round 14
// 161.289 us; speedup vs baseline: 1.1546x; 1.0095x over previous
//
#include <hip/hip_runtime.h>
#include <hip/hip_bf16.h>

#define B_   2
#define T_   2048
#define C_   1024
#define H_   16
#define KV_  4
#define HD_  64
#define M_   (B_*T_)     // 4096 tokens
#define PST_ 72          // P LDS row stride (bf16): 144 B
#define OST_ 68          // Obuf row stride (fp32): 272 B = 17x16 (64 would alias all rows
                         // onto the same banks: 256B = 2x128 -> 4-way conflict on merge)
#define M8L2E_ 11.5415603f   // 8 * log2(e)

typedef __bf16 bf16x8 __attribute__((ext_vector_type(8)));
typedef float  f32x4  __attribute__((ext_vector_type(4)));

static __device__ __forceinline__ unsigned short f2bf(float f) {
    __hip_bfloat16 h = __float2bfloat16(f);
    return __builtin_bit_cast(unsigned short, h);
}
static __device__ __forceinline__ unsigned int pk2(float a, float b) {
    return (unsigned int)f2bf(a) | ((unsigned int)f2bf(b) << 16);
}
// truncation pack (RTZ for positive values): 3 bit-ops vs ~12 for RNE pk2. Valid ONLY for
// P (softmax weights): P>=0 and O = sum(P*V)/sum(P) renormalizes -> pack error cancels.
static __device__ __forceinline__ unsigned int pk2t(float a, float b) {
    return (__builtin_bit_cast(unsigned int, a) >> 16)
         | (__builtin_bit_cast(unsigned int, b) & 0xFFFF0000u);
}
// NOTE (r6 failure): v_cvt_pk_bf16_f32 inline asm produced absmax 1.83 — never reintroduce
// without isolated refcheck.
// NOTE (r10 failure): fp32-A gemm1 cost +6us. Keep prep x-cast + bf16 gemm A.
// NOTE (r12 failure): K-split gemm2 via per-lane fp32 atomics cost +22us. Keep plain gemm2.

// ---------------------------------------------------------------- prep: cast x + 4 weight transposes
__global__ void prep_kernel(const float* __restrict__ x, unsigned short* __restrict__ xb,
                            const float* __restrict__ Wq, const float* __restrict__ Wk,
                            const float* __restrict__ Wv, const float* __restrict__ Wo,
                            unsigned short* __restrict__ wtqkv, unsigned short* __restrict__ wto) {
    __shared__ float tile[32][33];
    int bid = blockIdx.x;
    if (bid < 4096) {   // cast x -> bf16
        int i = (bid * 256 + threadIdx.x) * 4;
        float4 v = *(const float4*)(x + i);
        ushort4 o = make_ushort4(f2bf(v.x), f2bf(v.y), f2bf(v.z), f2bf(v.w));
        *(ushort4*)(xb + i) = o;
        return;
    }
    bid -= 4096;
    const float* src; unsigned short* dst; int s, nlog;
    if (bid < 1024)      { src = Wq; dst = wtqkv;               s = bid;        nlog = 5; }
    else if (bid < 1280) { src = Wk; dst = wtqkv + 1024 * 1024; s = bid - 1024; nlog = 3; }
    else if (bid < 1536) { src = Wv; dst = wtqkv + 1280 * 1024; s = bid - 1280; nlog = 3; }
    else                 { src = Wo; dst = wto;                 s = bid - 1536; nlog = 5; }
    int N  = 32 << nlog;
    int k0 = (s >> nlog) * 32, n0 = (s & ((1 << nlog) - 1)) * 32;
    int lr = threadIdx.x >> 5, lc = threadIdx.x & 31;
    #pragma unroll
    for (int i = 0; i < 4; i++) {
        int r = lr + i * 8;
        tile[r][lc] = src[(k0 + r) * N + n0 + lc];
    }
    __syncthreads();
    #pragma unroll
    for (int i = 0; i < 4; i++) {
        int r = lr + i * 8;
        dst[(n0 + r) * 1024 + k0 + lc] = f2bf(tile[lc][r]);
    }
}

// ------------------------------------------------ 128x64 bf16 MFMA GEMM, K=1024, BK=64
// 1D grid with BIJECTIVE XCD-CHUNK SWIZZLE (T1), m-major within XCD (r7: -3.7us total).
// ROPE=true epilogues (r14: ALL heads now fragment-ordered so every attn load is one
// contiguous 1KB wave load — K/V since r5 (attn 73->49us), Q added r14 since its
// tile-prologue gathers sit serially at tile start on a zero-tail grid):
//   0..15 q (RoPE+RMS, *0.125*log2e) -> qfb frag order (t>>4)*1024+(d>>5)*512+(t&15)*32+(d&31)
//   16..19 k (RoPE+RMS)              -> ktb same frag order
//   20..23 v                         -> vfb frag order ((t>>5)*4+(d>>4))*512+(d&15)*32+(t&31)
template <typename T, bool ROPE, int NH>
__global__ __launch_bounds__(256) void gemm_kernel(const unsigned short* __restrict__ A,
                                                   const unsigned short* __restrict__ Bt,
                                                   T* __restrict__ Cm, int Ni,
                                                   const float* __restrict__ cosb,
                                                   const float* __restrict__ sinb,
                                                   unsigned short* __restrict__ vfb,
                                                   unsigned short* __restrict__ ktb,
                                                   unsigned short* __restrict__ qfb) {
    __shared__ __align__(16) unsigned short As[2][128 * 32];
    __shared__ __align__(16) unsigned short Bs[2][64 * 32];
    int bid = blockIdx.x;
    int swz = (bid & 7) * (NH * 4) + (bid >> 3);   // nwg = NH*32, divisible by 8
    int head = swz % NH;
    int m0 = (swz / NH) * 128;
    int n0 = head * 64;
    int tid = threadIdx.x;
    int w = tid >> 6, lane = tid & 63;
    int col = lane & 15, quad = lane >> 4;
    int wm = w * 32;
    int ar = tid >> 2, ak = (tid & 3) * 8;

    f32x4 acc[2][4];
    #pragma unroll
    for (int mt = 0; mt < 2; mt++)
        #pragma unroll
        for (int nt = 0; nt < 4; nt++) acc[mt][nt] = (f32x4){0.f, 0.f, 0.f, 0.f};

    for (int k0 = 0; k0 < 1024; k0 += 64) {
        #pragma unroll
        for (int hh = 0; hh < 2; hh++) {
            __builtin_amdgcn_global_load_lds(
                (const __attribute__((address_space(1))) unsigned int*)(A + (size_t)(m0 + ar) * 1024 + k0 + hh * 32 + ak),
                (__attribute__((address_space(3))) unsigned int*)(&As[hh][ar * 32 + ak]), 16, 0, 0);
            __builtin_amdgcn_global_load_lds(
                (const __attribute__((address_space(1))) unsigned int*)(A + (size_t)(m0 + ar + 64) * 1024 + k0 + hh * 32 + ak),
                (__attribute__((address_space(3))) unsigned int*)(&As[hh][(ar + 64) * 32 + ak]), 16, 0, 0);
            __builtin_amdgcn_global_load_lds(
                (const __attribute__((address_space(1))) unsigned int*)(Bt + (size_t)(n0 + ar) * 1024 + k0 + hh * 32 + ak),
                (__attribute__((address_space(3))) unsigned int*)(&Bs[hh][ar * 32 + ak]), 16, 0, 0);
        }
        __syncthreads();
        bf16x8 af[2][2], bfr[4][2];
        #pragma unroll
        for (int hh = 0; hh < 2; hh++) {
            #pragma unroll
            for (int mt = 0; mt < 2; mt++) af[mt][hh]  = *(const bf16x8*)&As[hh][(wm + mt * 16 + col) * 32 + quad * 8];
            #pragma unroll
            for (int nt = 0; nt < 4; nt++) bfr[nt][hh] = *(const bf16x8*)&Bs[hh][(nt * 16 + col) * 32 + quad * 8];
        }
        #pragma unroll
        for (int hh = 0; hh < 2; hh++)
            #pragma unroll
            for (int mt = 0; mt < 2; mt++)
                #pragma unroll
                for (int nt = 0; nt < 4; nt++)
                    acc[mt][nt] = __builtin_amdgcn_mfma_f32_16x16x32_bf16(af[mt][hh], bfr[nt][hh], acc[mt][nt], 0, 0, 0);
        __syncthreads();
    }

    if constexpr (ROPE) {
        int b = m0 >> 11;
        if (head >= H_ + KV_) {
            // v head: fragment-ordered vfb write, uint2 (4 consecutive t at fixed d); RNE pack
            int kvh = head - (H_ + KV_);
            unsigned short* vbase = vfb + (size_t)(b * KV_ + kvh) * (T_ * 64);
            #pragma unroll
            for (int mt = 0; mt < 2; mt++) {
                int tb = (m0 + wm + mt * 16 + quad * 4) & (T_ - 1);
                #pragma unroll
                for (int nt = 0; nt < 4; nt++) {
                    uint2 pv;
                    pv.x = pk2(acc[mt][nt][0], acc[mt][nt][1]);
                    pv.y = pk2(acc[mt][nt][2], acc[mt][nt][3]);
                    *(uint2*)&vbase[((tb >> 5) * 4 + nt) * 512 + col * 32 + (tb & 31)] = pv;
                }
            }
            return;
        }
        // q/k head: RoPE + RMSNorm
        #pragma unroll
        for (int mt = 0; mt < 2; mt++)
            #pragma unroll
            for (int r = 0; r < 4; r++) {
                int t = (m0 + wm + mt * 16 + quad * 4 + r) & (T_ - 1);
                float nv[4];
                #pragma unroll
                for (int nt = 0; nt < 4; nt++) {
                    int i = (nt & 1) * 16 + col;
                    float c = cosb[t * 32 + i], s = sinb[t * 32 + i];
                    float v = acc[mt][nt][r], p = acc[mt][nt ^ 2][r];
                    nv[nt] = (nt < 2) ? (v * c + p * s) : (v * c - p * s);
                }
                float sq = nv[0] * nv[0] + nv[1] * nv[1] + nv[2] * nv[2] + nv[3] * nv[3];
                sq += __shfl_xor(sq, 1, 64);
                sq += __shfl_xor(sq, 2, 64);
                sq += __shfl_xor(sq, 4, 64);
                sq += __shfl_xor(sq, 8, 64);
                float rr = rsqrtf(sq * (1.0f / 64.0f) + 1e-6f);
                if (head < H_) rr *= 0.125f * 1.44269504f;   // attn scale * log2(e) folded into q
                #pragma unroll
                for (int nt = 0; nt < 4; nt++) acc[mt][nt][r] = nv[nt] * rr;
            }
        // q and k heads: fragment-ordered writes (elementwise, same count as generic C-write)
        unsigned short* fbase = (head < H_)
            ? qfb + (size_t)(b * H_ + head) * (T_ * 64)
            : ktb + (size_t)(b * KV_ + (head - H_)) * (T_ * 64);
        #pragma unroll
        for (int mt = 0; mt < 2; mt++)
            #pragma unroll
            for (int r = 0; r < 4; r++) {
                int t = (m0 + wm + mt * 16 + quad * 4 + r) & (T_ - 1);
                #pragma unroll
                for (int nt = 0; nt < 4; nt++) {
                    int dd = nt * 16 + col;
                    fbase[(t >> 4) * 1024 + (dd >> 5) * 512 + (t & 15) * 32 + (dd & 31)] = f2bf(acc[mt][nt][r]);
                }
            }
        return;
    }

    #pragma unroll
    for (int mt = 0; mt < 2; mt++)
        #pragma unroll
        for (int nt = 0; nt < 4; nt++)
            #pragma unroll
            for (int r = 0; r < 4; r++) {
                size_t idx = (size_t)(m0 + wm + mt * 16 + quad * 4 + r) * Ni + n0 + nt * 16 + col;
                if constexpr (sizeof(T) == 2) Cm[idx] = f2bf(acc[mt][nt][r]);
                else                          Cm[idx] = acc[mt][nt][r];
            }
}

// ------------------------------------------------ MFMA flash attention: split-K, S^T trick
// r13 proven core (46.6us): r7 structure + T5 setprio + pk2t P-pack.
// r14: (a) Obuf rows padded 64->68 fp32 (256B stride aliased every row onto the same
// banks: merge writes were 4-way conflicted, reads 2x over floor); (b) Q loads now from
// fragment-ordered qfb — tile-prologue was 8x 16-line gathers, now 8 contiguous 1KB loads.
// Fragment-ordered ktb/vfb (r5: attn 73->49). BALANCED PAIRING: 1024 identical blocks.
// NOTE: plain __launch_bounds__(256). min-waves=4 once forced VGPR 64 -> spill. Never re-add.
// QK^T TRANSPOSED (A=K, B=Q); P->LDS b64; PV reads P q-major b128 (all-register PV
// regressed r3; K-prefetch null r8). Fixed-max softmax via exp2 (log2e folded into q).
__global__ __launch_bounds__(256) void attn_kernel(const unsigned short* __restrict__ qfb,
                                                   const unsigned short* __restrict__ ktb,
                                                   const unsigned short* __restrict__ vfb,
                                                   unsigned short* __restrict__ yb) {
    __shared__ __align__(16) char smem[4 * 32 * OST_ * 4];   // 34.8 KB: P stripes / padded Obuf
    __shared__ float lbuf[4][32];

    int bh = blockIdx.x & 31;
    int pi = blockIdx.x >> 5;               // pair index 0..31
    int b = bh >> 4, h = bh & 15, kvh = h >> 2;
    int tid = threadIdx.x;
    int w = tid >> 6, lane = tid & 63;
    int col = lane & 15, quad = lane >> 4;

    unsigned short* Ps = (unsigned short*)smem + w * (32 * PST_);
    float* Obuf = (float*)smem;

    const unsigned short* qfp = qfb + (size_t)(b * H_ + h) * (T_ * 64);
    const unsigned short* kfb = ktb + (size_t)(b * KV_ + kvh) * (T_ * 64);
    const unsigned short* vfp = vfb + (size_t)(b * KV_ + kvh) * (T_ * 64);

    bf16x8 ones;
    #pragma unroll
    for (int j = 0; j < 8; j++) ones[j] = (__bf16)1.0f;

    for (int ti = 0; ti < 2; ti++) {
        int qt = ti ? pi : 63 - pi;         // big tile first
        int t0 = qt * 32;
        int nkt = (t0 + 95) >> 6;           // 64-key tiles covering keys <= t0+31
        int we = ti ? 3 - w : w;            // reversed wave order on 2nd tile

        // Q B-frags (loop-invariant per tile): contiguous 1KB wave loads from qfb
        bf16x8 aq[2][2];
        #pragma unroll
        for (int ntq = 0; ntq < 2; ntq++)
            #pragma unroll
            for (int step = 0; step < 2; step++)
                aq[ntq][step] = *(const bf16x8*)&qfp[(qt * 2 + ntq) * 1024 + step * 512
                                                     + col * 32 + quad * 8];

        f32x4 o[2][4], lacc[2];
        #pragma unroll
        for (int mt = 0; mt < 2; mt++) {
            lacc[mt] = (f32x4){0.f, 0.f, 0.f, 0.f};
            #pragma unroll
            for (int nt = 0; nt < 4; nt++) o[mt][nt] = (f32x4){0.f, 0.f, 0.f, 0.f};
        }

        for (int kt = we; kt < nkt; kt += 4) {
            // S^T = K Q^T : A-frag = K rows (key), B-frag = Q
            f32x4 sacc[4][2];
            #pragma unroll
            for (int mtk = 0; mtk < 4; mtk++)
                #pragma unroll
                for (int ntq = 0; ntq < 2; ntq++) sacc[mtk][ntq] = (f32x4){0.f, 0.f, 0.f, 0.f};
            #pragma unroll
            for (int step = 0; step < 2; step++) {
                bf16x8 kb[4];
                #pragma unroll
                for (int mtk = 0; mtk < 4; mtk++)
                    kb[mtk] = *(const bf16x8*)&kfb[(kt * 4 + mtk) * 1024 + step * 512 + col * 32 + quad * 8];
                __builtin_amdgcn_s_setprio(1);
                #pragma unroll
                for (int mtk = 0; mtk < 4; mtk++)
                    #pragma unroll
                    for (int ntq = 0; ntq < 2; ntq++)
                        sacc[mtk][ntq] = __builtin_amdgcn_mfma_f32_16x16x32_bf16(kb[mtk], aq[ntq][step], sacc[mtk][ntq], 0, 0, 0);
                __builtin_amdgcn_s_setprio(0);
            }
            // issue V loads (contiguous 1KB each); latency hides under exp/pack
            bf16x8 vb[2][4];
            #pragma unroll
            for (int step = 0; step < 2; step++)
                #pragma unroll
                for (int ntd = 0; ntd < 4; ntd++)
                    vb[step][ntd] = *(const bf16x8*)&vfp[((kt * 2 + step) * 4 + ntd) * 512 + col * 32 + quad * 8];
            if (kt == nkt - 1) {   // diagonal: causal mask (S^T indices: row=key, col=q)
                #pragma unroll
                for (int mtk = 0; mtk < 4; mtk++)
                    #pragma unroll
                    for (int ntq = 0; ntq < 2; ntq++)
                        #pragma unroll
                        for (int r = 0; r < 4; r++)
                            if (kt * 64 + mtk * 16 + quad * 4 + r > t0 + ntq * 16 + col)
                                sacc[mtk][ntq][r] = -1e30f;
            }
            // p = 2^(s' - 8*log2e); truncation pack (pk2t) — error cancels in renorm
            #pragma unroll
            for (int mtk = 0; mtk < 4; mtk++)
                #pragma unroll
                for (int ntq = 0; ntq < 2; ntq++) {
                    uint2 pw;
                    pw.x = pk2t(__builtin_amdgcn_exp2f(sacc[mtk][ntq][0] - M8L2E_),
                                __builtin_amdgcn_exp2f(sacc[mtk][ntq][1] - M8L2E_));
                    pw.y = pk2t(__builtin_amdgcn_exp2f(sacc[mtk][ntq][2] - M8L2E_),
                                __builtin_amdgcn_exp2f(sacc[mtk][ntq][3] - M8L2E_));
                    *(uint2*)&Ps[(ntq * 16 + col) * PST_ + mtk * 16 + quad * 4] = pw;
                }
            // O += P V ; l += P * ones  (P read q-major as A-frag, b128)
            #pragma unroll
            for (int step = 0; step < 2; step++) {
                bf16x8 ap[2];
                #pragma unroll
                for (int mtq = 0; mtq < 2; mtq++)
                    ap[mtq] = *(const bf16x8*)&Ps[(mtq * 16 + col) * PST_ + quad * 8 + step * 32];
                __builtin_amdgcn_s_setprio(1);
                #pragma unroll
                for (int ntd = 0; ntd < 4; ntd++)
                    #pragma unroll
                    for (int mtq = 0; mtq < 2; mtq++)
                        o[mtq][ntd] = __builtin_amdgcn_mfma_f32_16x16x32_bf16(ap[mtq], vb[step][ntd], o[mtq][ntd], 0, 0, 0);
                #pragma unroll
                for (int mtq = 0; mtq < 2; mtq++)
                    lacc[mtq] = __builtin_amdgcn_mfma_f32_16x16x32_bf16(ap[mtq], ones, lacc[mtq], 0, 0, 0);
                __builtin_amdgcn_s_setprio(0);
            }
        }

        __syncthreads();   // all waves done with P space
        #pragma unroll
        for (int mt = 0; mt < 2; mt++)
            #pragma unroll
            for (int nt = 0; nt < 4; nt++)
                #pragma unroll
                for (int r = 0; r < 4; r++)
                    Obuf[w * (32 * OST_) + (mt * 16 + quad * 4 + r) * OST_ + nt * 16 + col] = o[mt][nt][r];
        if (col == 0) {
            #pragma unroll
            for (int mt = 0; mt < 2; mt++)
                #pragma unroll
                for (int r = 0; r < 4; r++)
                    lbuf[w][mt * 16 + quad * 4 + r] = lacc[mt][r];
        }
        __syncthreads();
        {
            int row = tid >> 3, d0 = (tid & 7) * 8;
            float ls = lbuf[0][row] + lbuf[1][row] + lbuf[2][row] + lbuf[3][row];
            float inv = 1.0f / ls;
            float s[8];
            #pragma unroll
            for (int j = 0; j < 8; j++) s[j] = 0.f;
            #pragma unroll
            for (int wv = 0; wv < 4; wv++) {
                f32x4 p0 = *(const f32x4*)&Obuf[wv * (32 * OST_) + row * OST_ + d0];
                f32x4 p1 = *(const f32x4*)&Obuf[wv * (32 * OST_) + row * OST_ + d0 + 4];
                #pragma unroll
                for (int j = 0; j < 4; j++) { s[j] += p0[j]; s[4 + j] += p1[j]; }
            }
            unsigned short o8[8];
            #pragma unroll
            for (int j = 0; j < 8; j++) o8[j] = f2bf(s[j] * inv);
            *(uint4*)&yb[(size_t)(b * T_ + t0 + row) * C_ + h * 64 + d0] = *(uint4*)o8;
        }
        __syncthreads();   // merge reads done before next tile reuses Obuf
    }
}

// ---------------------------------------------------------------- launch
extern "C" void kernel_launch(void* const* d_in, const int* in_sizes, int n_in,
                              void* d_out, int out_size, void* d_ws, size_t ws_size,
                              hipStream_t stream) {
    const float* x    = (const float*)d_in[0];
    const float* cosb = (const float*)d_in[1];
    const float* sinb = (const float*)d_in[2];
    const float* Wq   = (const float*)d_in[3];
    const float* Wk   = (const float*)d_in[4];
    const float* Wv   = (const float*)d_in[5];
    const float* Wo   = (const float*)d_in[6];
    float* out = (float*)d_out;

    char* ws = (char*)d_ws;
    unsigned short* xb    = (unsigned short*)(ws);               // 8 MB (reused as yb)
    unsigned short* yb    = (unsigned short*)(ws);               // alias: xb dead after QKV GEMM
    unsigned short* wtqkv = (unsigned short*)(ws + ( 8u << 20)); // 3 MB
    unsigned short* wto   = (unsigned short*)(ws + (11u << 20)); // 2 MB
    unsigned short* qfb   = (unsigned short*)(ws + (13u << 20)); // 8 MB fragment-ordered Q
    unsigned short* vfb   = (unsigned short*)(ws + (21u << 20)); // 2 MB fragment-ordered V
    unsigned short* ktb   = (unsigned short*)(ws + (23u << 20)); // 2 MB fragment-ordered K

    prep_kernel<<<4096 + 2560, 256, 0, stream>>>(x, xb, Wq, Wk, Wv, Wo, wtqkv, wto);
    // QKV projection + fused RoPE/RMSNorm; q -> qfb, k -> ktb, v -> vfb (all frag order)
    // 1D grid 768 = 24 heads x 32 m-blocks, XCD-chunk swizzled (m-major per XCD)
    gemm_kernel<unsigned short, true, 24><<<768, 256, 0, stream>>>(xb, wtqkv, (unsigned short*)nullptr, 0, cosb, sinb, vfb, ktb, qfb);
    // split-K flash attention: balanced qt-pairing, all-frag-ordered loads, setprio, padded Obuf
    attn_kernel<<<1024, 256, 0, stream>>>(qfb, ktb, vfb, yb);
    // output projection -> fp32 out; 1D grid 512 = 16 x 32, XCD-chunk swizzled
    gemm_kernel<float, false, 16><<<512, 256, 0, stream>>>(yb, wto, out, C_, nullptr, nullptr, nullptr, nullptr, nullptr);
}

// Round 15
// 160.410 us; speedup vs baseline: 1.1609x; 1.0055x over previous
//
#include <hip/hip_runtime.h>
#include <hip/hip_bf16.h>

#define B_   2
#define T_   2048
#define C_   1024
#define H_   16
#define KV_  4
#define HD_  64
#define M_   (B_*T_)     // 4096 tokens
#define PST_ 88          // P LDS row stride (bf16): 176 B = 11x16 (b128-aligned); banks for
                         // P-reads (44c+4q mod 32) and writes land <=2-way (col,col+8 alias
                         // only) vs 4-way at 72. P region 22.5KB < 34.8KB smem.
#define OST_ 68          // Obuf row stride (fp32): 272 B (64 aliased all rows to same banks)
#define M8L2E_ 11.5415603f   // 8 * log2(e)

typedef __bf16 bf16x8 __attribute__((ext_vector_type(8)));
typedef float  f32x4  __attribute__((ext_vector_type(4)));

static __device__ __forceinline__ unsigned short f2bf(float f) {
    __hip_bfloat16 h = __float2bfloat16(f);
    return __builtin_bit_cast(unsigned short, h);
}
static __device__ __forceinline__ unsigned int pk2(float a, float b) {
    return (unsigned int)f2bf(a) | ((unsigned int)f2bf(b) << 16);
}
// truncation pack (RTZ for positive values): 3 bit-ops vs ~12 for RNE pk2. Valid ONLY for
// P (softmax weights): P>=0 and O = sum(P*V)/sum(P) renormalizes -> pack error cancels.
static __device__ __forceinline__ unsigned int pk2t(float a, float b) {
    return (__builtin_bit_cast(unsigned int, a) >> 16)
         | (__builtin_bit_cast(unsigned int, b) & 0xFFFF0000u);
}
// NOTE (r6): v_cvt_pk_bf16_f32 inline asm gave absmax 1.83 — never without isolated refcheck.
// NOTE (r10): fp32-A gemm1 cost +6us. Keep prep x-cast + bf16 gemm A.
// NOTE (r12): K-split gemm2 via per-lane fp32 atomics cost +22us. Keep plain gemm2.
// NOTE (r15): barrier BEFORE Obuf writes is REQUIRED — wave w's Obuf region overlaps wave
// w+1's P stripe; r2-r14 ran without it (stable only by wave-balance timing luck).

// ---------------------------------------------------------------- prep: cast x + 4 weight transposes
__global__ void prep_kernel(const float* __restrict__ x, unsigned short* __restrict__ xb,
                            const float* __restrict__ Wq, const float* __restrict__ Wk,
                            const float* __restrict__ Wv, const float* __restrict__ Wo,
                            unsigned short* __restrict__ wtqkv, unsigned short* __restrict__ wto) {
    __shared__ float tile[32][33];
    int bid = blockIdx.x;
    if (bid < 4096) {   // cast x -> bf16
        int i = (bid * 256 + threadIdx.x) * 4;
        float4 v = *(const float4*)(x + i);
        ushort4 o = make_ushort4(f2bf(v.x), f2bf(v.y), f2bf(v.z), f2bf(v.w));
        *(ushort4*)(xb + i) = o;
        return;
    }
    bid -= 4096;
    const float* src; unsigned short* dst; int s, nlog;
    if (bid < 1024)      { src = Wq; dst = wtqkv;               s = bid;        nlog = 5; }
    else if (bid < 1280) { src = Wk; dst = wtqkv + 1024 * 1024; s = bid - 1024; nlog = 3; }
    else if (bid < 1536) { src = Wv; dst = wtqkv + 1280 * 1024; s = bid - 1280; nlog = 3; }
    else                 { src = Wo; dst = wto;                 s = bid - 1536; nlog = 5; }
    int N  = 32 << nlog;
    int k0 = (s >> nlog) * 32, n0 = (s & ((1 << nlog) - 1)) * 32;
    int lr = threadIdx.x >> 5, lc = threadIdx.x & 31;
    #pragma unroll
    for (int i = 0; i < 4; i++) {
        int r = lr + i * 8;
        tile[r][lc] = src[(k0 + r) * N + n0 + lc];
    }
    __syncthreads();
    #pragma unroll
    for (int i = 0; i < 4; i++) {
        int r = lr + i * 8;
        dst[(n0 + r) * 1024 + k0 + lc] = f2bf(tile[lc][r]);
    }
}

// ------------------------------------------------ 128x64 bf16 MFMA GEMM, K=1024, BK=64
// 1D grid with BIJECTIVE XCD-CHUNK SWIZZLE (T1), m-major within XCD (r7: -3.7us total).
// ROPE=true epilogues (ALL heads fragment-ordered so every attn load is one contiguous
// 1KB wave load — K/V since r5 (attn 73->49us), Q since r14):
//   0..15 q (RoPE+RMS, *0.125*log2e) -> qfb frag order (t>>4)*1024+(d>>5)*512+(t&15)*32+(d&31)
//   16..19 k (RoPE+RMS)              -> ktb same frag order
//   20..23 v                         -> vfb frag order ((t>>5)*4+(d>>4))*512+(d&15)*32+(t&31)
template <typename T, bool ROPE, int NH>
__global__ __launch_bounds__(256) void gemm_kernel(const unsigned short* __restrict__ A,
                                                   const unsigned short* __restrict__ Bt,
                                                   T* __restrict__ Cm, int Ni,
                                                   const float* __restrict__ cosb,
                                                   const float* __restrict__ sinb,
                                                   unsigned short* __restrict__ vfb,
                                                   unsigned short* __restrict__ ktb,
                                                   unsigned short* __restrict__ qfb) {
    __shared__ __align__(16) unsigned short As[2][128 * 32];
    __shared__ __align__(16) unsigned short Bs[2][64 * 32];
    int bid = blockIdx.x;
    int swz = (bid & 7) * (NH * 4) + (bid >> 3);   // nwg = NH*32, divisible by 8
    int head = swz % NH;
    int m0 = (swz / NH) * 128;
    int n0 = head * 64;
    int tid = threadIdx.x;
    int w = tid >> 6, lane = tid & 63;
    int col = lane & 15, quad = lane >> 4;
    int wm = w * 32;
    int ar = tid >> 2, ak = (tid & 3) * 8;

    f32x4 acc[2][4];
    #pragma unroll
    for (int mt = 0; mt < 2; mt++)
        #pragma unroll
        for (int nt = 0; nt < 4; nt++) acc[mt][nt] = (f32x4){0.f, 0.f, 0.f, 0.f};

    for (int k0 = 0; k0 < 1024; k0 += 64) {
        #pragma unroll
        for (int hh = 0; hh < 2; hh++) {
            __builtin_amdgcn_global_load_lds(
                (const __attribute__((address_space(1))) unsigned int*)(A + (size_t)(m0 + ar) * 1024 + k0 + hh * 32 + ak),
                (__attribute__((address_space(3))) unsigned int*)(&As[hh][ar * 32 + ak]), 16, 0, 0);
            __builtin_amdgcn_global_load_lds(
                (const __attribute__((address_space(1))) unsigned int*)(A + (size_t)(m0 + ar + 64) * 1024 + k0 + hh * 32 + ak),
                (__attribute__((address_space(3))) unsigned int*)(&As[hh][(ar + 64) * 32 + ak]), 16, 0, 0);
            __builtin_amdgcn_global_load_lds(
                (const __attribute__((address_space(1))) unsigned int*)(Bt + (size_t)(n0 + ar) * 1024 + k0 + hh * 32 + ak),
                (__attribute__((address_space(3))) unsigned int*)(&Bs[hh][ar * 32 + ak]), 16, 0, 0);
        }
        __syncthreads();
        bf16x8 af[2][2], bfr[4][2];
        #pragma unroll
        for (int hh = 0; hh < 2; hh++) {
            #pragma unroll
            for (int mt = 0; mt < 2; mt++) af[mt][hh]  = *(const bf16x8*)&As[hh][(wm + mt * 16 + col) * 32 + quad * 8];
            #pragma unroll
            for (int nt = 0; nt < 4; nt++) bfr[nt][hh] = *(const bf16x8*)&Bs[hh][(nt * 16 + col) * 32 + quad * 8];
        }
        #pragma unroll
        for (int hh = 0; hh < 2; hh++)
            #pragma unroll
            for (int mt = 0; mt < 2; mt++)
                #pragma unroll
                for (int nt = 0; nt < 4; nt++)
                    acc[mt][nt] = __builtin_amdgcn_mfma_f32_16x16x32_bf16(af[mt][hh], bfr[nt][hh], acc[mt][nt], 0, 0, 0);
        __syncthreads();
    }

    if constexpr (ROPE) {
        int b = m0 >> 11;
        if (head >= H_ + KV_) {
            // v head: fragment-ordered vfb write, uint2 (4 consecutive t at fixed d); RNE pack
            int kvh = head - (H_ + KV_);
            unsigned short* vbase = vfb + (size_t)(b * KV_ + kvh) * (T_ * 64);
            #pragma unroll
            for (int mt = 0; mt < 2; mt++) {
                int tb = (m0 + wm + mt * 16 + quad * 4) & (T_ - 1);
                #pragma unroll
                for (int nt = 0; nt < 4; nt++) {
                    uint2 pv;
                    pv.x = pk2(acc[mt][nt][0], acc[mt][nt][1]);
                    pv.y = pk2(acc[mt][nt][2], acc[mt][nt][3]);
                    *(uint2*)&vbase[((tb >> 5) * 4 + nt) * 512 + col * 32 + (tb & 31)] = pv;
                }
            }
            return;
        }
        // q/k head: RoPE + RMSNorm
        #pragma unroll
        for (int mt = 0; mt < 2; mt++)
            #pragma unroll
            for (int r = 0; r < 4; r++) {
                int t = (m0 + wm + mt * 16 + quad * 4 + r) & (T_ - 1);
                float nv[4];
                #pragma unroll
                for (int nt = 0; nt < 4; nt++) {
                    int i = (nt & 1) * 16 + col;
                    float c = cosb[t * 32 + i], s = sinb[t * 32 + i];
                    float v = acc[mt][nt][r], p = acc[mt][nt ^ 2][r];
                    nv[nt] = (nt < 2) ? (v * c + p * s) : (v * c - p * s);
                }
                float sq = nv[0] * nv[0] + nv[1] * nv[1] + nv[2] * nv[2] + nv[3] * nv[3];
                sq += __shfl_xor(sq, 1, 64);
                sq += __shfl_xor(sq, 2, 64);
                sq += __shfl_xor(sq, 4, 64);
                sq += __shfl_xor(sq, 8, 64);
                float rr = rsqrtf(sq * (1.0f / 64.0f) + 1e-6f);
                if (head < H_) rr *= 0.125f * 1.44269504f;   // attn scale * log2(e) folded into q
                #pragma unroll
                for (int nt = 0; nt < 4; nt++) acc[mt][nt][r] = nv[nt] * rr;
            }
        // q and k heads: fragment-ordered writes (elementwise, same count as generic C-write)
        unsigned short* fbase = (head < H_)
            ? qfb + (size_t)(b * H_ + head) * (T_ * 64)
            : ktb + (size_t)(b * KV_ + (head - H_)) * (T_ * 64);
        #pragma unroll
        for (int mt = 0; mt < 2; mt++)
            #pragma unroll
            for (int r = 0; r < 4; r++) {
                int t = (m0 + wm + mt * 16 + quad * 4 + r) & (T_ - 1);
                #pragma unroll
                for (int nt = 0; nt < 4; nt++) {
                    int dd = nt * 16 + col;
                    fbase[(t >> 4) * 1024 + (dd >> 5) * 512 + (t & 15) * 32 + (dd & 31)] = f2bf(acc[mt][nt][r]);
                }
            }
        return;
    }

    #pragma unroll
    for (int mt = 0; mt < 2; mt++)
        #pragma unroll
        for (int nt = 0; nt < 4; nt++)
            #pragma unroll
            for (int r = 0; r < 4; r++) {
                size_t idx = (size_t)(m0 + wm + mt * 16 + quad * 4 + r) * Ni + n0 + nt * 16 + col;
                if constexpr (sizeof(T) == 2) Cm[idx] = f2bf(acc[mt][nt][r]);
                else                          Cm[idx] = acc[mt][nt][r];
            }
}

// ------------------------------------------------ MFMA flash attention: split-K, S^T trick
// r14 core (46.8us) + r15: (a) PST 72->88: P-read was the remaining ~1.9M conflict cycles
// (4-way at 144B stride); 176B=11x16 keeps b128 alignment and lands both P ops <=2-way
// (free, m136). (b) barrier added BEFORE Obuf writes — closes the latent Obuf/P-stripe
// overlap race (see NOTE r15). (c) trailing barrier skipped on last tile (net +1 barrier).
// Fragment-ordered qfb/ktb/vfb: every load one contiguous 1KB wave load (r5/r14).
// BALANCED PAIRING: 1024 identical blocks, all co-resident, zero tail.
// T5 setprio around MFMA clusters (r11, -3%). pk2t P-pack (r13, -1us).
// NOTE: plain __launch_bounds__(256). min-waves=4 once forced VGPR 64 -> spill. Never re-add.
// QK^T TRANSPOSED (A=K, B=Q); P->LDS b64; PV reads P q-major b128 (all-register PV
// regressed r3; K-prefetch null r8). Fixed-max softmax via exp2 (log2e folded into q).
__global__ __launch_bounds__(256) void attn_kernel(const unsigned short* __restrict__ qfb,
                                                   const unsigned short* __restrict__ ktb,
                                                   const unsigned short* __restrict__ vfb,
                                                   unsigned short* __restrict__ yb) {
    __shared__ __align__(16) char smem[4 * 32 * OST_ * 4];   // 34.8 KB: P stripes (22.5K) / Obuf
    __shared__ float lbuf[4][32];

    int bh = blockIdx.x & 31;
    int pi = blockIdx.x >> 5;               // pair index 0..31
    int b = bh >> 4, h = bh & 15, kvh = h >> 2;
    int tid = threadIdx.x;
    int w = tid >> 6, lane = tid & 63;
    int col = lane & 15, quad = lane >> 4;

    unsigned short* Ps = (unsigned short*)smem + w * (32 * PST_);
    float* Obuf = (float*)smem;

    const unsigned short* qfp = qfb + (size_t)(b * H_ + h) * (T_ * 64);
    const unsigned short* kfb = ktb + (size_t)(b * KV_ + kvh) * (T_ * 64);
    const unsigned short* vfp = vfb + (size_t)(b * KV_ + kvh) * (T_ * 64);

    bf16x8 ones;
    #pragma unroll
    for (int j = 0; j < 8; j++) ones[j] = (__bf16)1.0f;

    for (int ti = 0; ti < 2; ti++) {
        int qt = ti ? pi : 63 - pi;         // big tile first
        int t0 = qt * 32;
        int nkt = (t0 + 95) >> 6;           // 64-key tiles covering keys <= t0+31
        int we = ti ? 3 - w : w;            // reversed wave order on 2nd tile

        // Q B-frags (loop-invariant per tile): contiguous 1KB wave loads from qfb
        bf16x8 aq[2][2];
        #pragma unroll
        for (int ntq = 0; ntq < 2; ntq++)
            #pragma unroll
            for (int step = 0; step < 2; step++)
                aq[ntq][step] = *(const bf16x8*)&qfp[(qt * 2 + ntq) * 1024 + step * 512
                                                     + col * 32 + quad * 8];

        f32x4 o[2][4], lacc[2];
        #pragma unroll
        for (int mt = 0; mt < 2; mt++) {
            lacc[mt] = (f32x4){0.f, 0.f, 0.f, 0.f};
            #pragma unroll
            for (int nt = 0; nt < 4; nt++) o[mt][nt] = (f32x4){0.f, 0.f, 0.f, 0.f};
        }

        for (int kt = we; kt < nkt; kt += 4) {
            // S^T = K Q^T : A-frag = K rows (key), B-frag = Q
            f32x4 sacc[4][2];
            #pragma unroll
            for (int mtk = 0; mtk < 4; mtk++)
                #pragma unroll
                for (int ntq = 0; ntq < 2; ntq++) sacc[mtk][ntq] = (f32x4){0.f, 0.f, 0.f, 0.f};
            #pragma unroll
            for (int step = 0; step < 2; step++) {
                bf16x8 kb[4];
                #pragma unroll
                for (int mtk = 0; mtk < 4; mtk++)
                    kb[mtk] = *(const bf16x8*)&kfb[(kt * 4 + mtk) * 1024 + step * 512 + col * 32 + quad * 8];
                __builtin_amdgcn_s_setprio(1);
                #pragma unroll
                for (int mtk = 0; mtk < 4; mtk++)
                    #pragma unroll
                    for (int ntq = 0; ntq < 2; ntq++)
                        sacc[mtk][ntq] = __builtin_amdgcn_mfma_f32_16x16x32_bf16(kb[mtk], aq[ntq][step], sacc[mtk][ntq], 0, 0, 0);
                __builtin_amdgcn_s_setprio(0);
            }
            // issue V loads (contiguous 1KB each); latency hides under exp/pack
            bf16x8 vb[2][4];
            #pragma unroll
            for (int step = 0; step < 2; step++)
                #pragma unroll
                for (int ntd = 0; ntd < 4; ntd++)
                    vb[step][ntd] = *(const bf16x8*)&vfp[((kt * 2 + step) * 4 + ntd) * 512 + col * 32 + quad * 8];
            if (kt == nkt - 1) {   // diagonal: causal mask (S^T indices: row=key, col=q)
                #pragma unroll
                for (int mtk = 0; mtk < 4; mtk++)
                    #pragma unroll
                    for (int ntq = 0; ntq < 2; ntq++)
                        #pragma unroll
                        for (int r = 0; r < 4; r++)
                            if (kt * 64 + mtk * 16 + quad * 4 + r > t0 + ntq * 16 + col)
                                sacc[mtk][ntq][r] = -1e30f;
            }
            // p = 2^(s' - 8*log2e); truncation pack (pk2t) — error cancels in renorm
            #pragma unroll
            for (int mtk = 0; mtk < 4; mtk++)
                #pragma unroll
                for (int ntq = 0; ntq < 2; ntq++) {
                    uint2 pw;
                    pw.x = pk2t(__builtin_amdgcn_exp2f(sacc[mtk][ntq][0] - M8L2E_),
                                __builtin_amdgcn_exp2f(sacc[mtk][ntq][1] - M8L2E_));
                    pw.y = pk2t(__builtin_amdgcn_exp2f(sacc[mtk][ntq][2] - M8L2E_),
                                __builtin_amdgcn_exp2f(sacc[mtk][ntq][3] - M8L2E_));
                    *(uint2*)&Ps[(ntq * 16 + col) * PST_ + mtk * 16 + quad * 4] = pw;
                }
            // O += P V ; l += P * ones  (P read q-major as A-frag, b128)
            #pragma unroll
            for (int step = 0; step < 2; step++) {
                bf16x8 ap[2];
                #pragma unroll
                for (int mtq = 0; mtq < 2; mtq++)
                    ap[mtq] = *(const bf16x8*)&Ps[(mtq * 16 + col) * PST_ + quad * 8 + step * 32];
                __builtin_amdgcn_s_setprio(1);
                #pragma unroll
                for (int ntd = 0; ntd < 4; ntd++)
                    #pragma unroll
                    for (int mtq = 0; mtq < 2; mtq++)
                        o[mtq][ntd] = __builtin_amdgcn_mfma_f32_16x16x32_bf16(ap[mtq], vb[step][ntd], o[mtq][ntd], 0, 0, 0);
                #pragma unroll
                for (int mtq = 0; mtq < 2; mtq++)
                    lacc[mtq] = __builtin_amdgcn_mfma_f32_16x16x32_bf16(ap[mtq], ones, lacc[mtq], 0, 0, 0);
                __builtin_amdgcn_s_setprio(0);
            }
        }

        __syncthreads();   // ALL waves done with P stripes before Obuf writes alias them (r15 fix)
        #pragma unroll
        for (int mt = 0; mt < 2; mt++)
            #pragma unroll
            for (int nt = 0; nt < 4; nt++)
                #pragma unroll
                for (int r = 0; r < 4; r++)
                    Obuf[w * (32 * OST_) + (mt * 16 + quad * 4 + r) * OST_ + nt * 16 + col] = o[mt][nt][r];
        if (col == 0) {
            #pragma unroll
            for (int mt = 0; mt < 2; mt++)
                #pragma unroll
                for (int r = 0; r < 4; r++)
                    lbuf[w][mt * 16 + quad * 4 + r] = lacc[mt][r];
        }
        __syncthreads();
        {
            int row = tid >> 3, d0 = (tid & 7) * 8;
            float ls = lbuf[0][row] + lbuf[1][row] + lbuf[2][row] + lbuf[3][row];
            float inv = 1.0f / ls;
            float s[8];
            #pragma unroll
            for (int j = 0; j < 8; j++) s[j] = 0.f;
            #pragma unroll
            for (int wv = 0; wv < 4; wv++) {
                f32x4 p0 = *(const f32x4*)&Obuf[wv * (32 * OST_) + row * OST_ + d0];
                f32x4 p1 = *(const f32x4*)&Obuf[wv * (32 * OST_) + row * OST_ + d0 + 4];
                #pragma unroll
                for (int j = 0; j < 4; j++) { s[j] += p0[j]; s[4 + j] += p1[j]; }
            }
            unsigned short o8[8];
            #pragma unroll
            for (int j = 0; j < 8; j++) o8[j] = f2bf(s[j] * inv);
            *(uint4*)&yb[(size_t)(b * T_ + t0 + row) * C_ + h * 64 + d0] = *(uint4*)o8;
        }
        if (ti == 0) __syncthreads();   // merge reads done before tile 1's P writes reuse smem
    }
}

// ---------------------------------------------------------------- launch
extern "C" void kernel_launch(void* const* d_in, const int* in_sizes, int n_in,
                              void* d_out, int out_size, void* d_ws, size_t ws_size,
                              hipStream_t stream) {
    const float* x    = (const float*)d_in[0];
    const float* cosb = (const float*)d_in[1];
    const float* sinb = (const float*)d_in[2];
    const float* Wq   = (const float*)d_in[3];
    const float* Wk   = (const float*)d_in[4];
    const float* Wv   = (const float*)d_in[5];
    const float* Wo   = (const float*)d_in[6];
    float* out = (float*)d_out;

    char* ws = (char*)d_ws;
    unsigned short* xb    = (unsigned short*)(ws);               // 8 MB (reused as yb)
    unsigned short* yb    = (unsigned short*)(ws);               // alias: xb dead after QKV GEMM
    unsigned short* wtqkv = (unsigned short*)(ws + ( 8u << 20)); // 3 MB
    unsigned short* wto   = (unsigned short*)(ws + (11u << 20)); // 2 MB
    unsigned short* qfb   = (unsigned short*)(ws + (13u << 20)); // 8 MB fragment-ordered Q
    unsigned short* vfb   = (unsigned short*)(ws + (21u << 20)); // 2 MB fragment-ordered V
    unsigned short* ktb   = (unsigned short*)(ws + (23u << 20)); // 2 MB fragment-ordered K

    prep_kernel<<<4096 + 2560, 256, 0, stream>>>(x, xb, Wq, Wk, Wv, Wo, wtqkv, wto);
    // QKV projection + fused RoPE/RMSNorm; q -> qfb, k -> ktb, v -> vfb (all frag order)
    // 1D grid 768 = 24 heads x 32 m-blocks, XCD-chunk swizzled (m-major per XCD)
    gemm_kernel<unsigned short, true, 24><<<768, 256, 0, stream>>>(xb, wtqkv, (unsigned short*)nullptr, 0, cosb, sinb, vfb, ktb, qfb);
    // split-K flash attention: balanced qt-pairing, frag-ordered loads, setprio, PST=88,
    // race-hardened barrier placement
    attn_kernel<<<1024, 256, 0, stream>>>(qfb, ktb, vfb, yb);
    // output projection -> fp32 out; 1D grid 512 = 16 x 32, XCD-chunk swizzled
    gemm_kernel<float, false, 16><<<512, 256, 0, stream>>>(yb, wto, out, C_, nullptr, nullptr, nullptr, nullptr, nullptr);
}